// Round 5
// baseline (302.914 us; speedup 1.0000x reference)
//
#include <hip/hip_runtime.h>

// ---- problem constants ----
#define BB 2
#define LL 2048
#define DMODEL 1024
#define DSSM 2048
#define NH 32
#define HD 64
#define DST 128
#define CONVD 2304
#define DPROJ 4384
#define CS 64               // SSD chunk size (rechunked; math is exact)
#define NC 32               // LL/CS
#define BLTOT (BB*LL)       // 4096

typedef short v8s __attribute__((ext_vector_type(8)));
typedef float v4f __attribute__((ext_vector_type(4)));

__device__ __forceinline__ float b2f(unsigned short h) {
  union { unsigned int u; float f; } v; v.u = ((unsigned int)h) << 16; return v.f;
}
__device__ __forceinline__ unsigned short f2b(float f) {
  union { float f; unsigned int u; } v; v.f = f;
  unsigned int u = v.u;
  return (unsigned short)((u + 0x7fffu + ((u >> 16) & 1u)) >> 16);
}
__device__ __forceinline__ v4f mfma16(v8s a, v8s b, v4f c) {
  return __builtin_amdgcn_mfma_f32_16x16x32_bf16(a, b, c, 0, 0, 0);
}
// async global->LDS, 16B per lane; LDS dest = wave-uniform base + lane*16
__device__ __forceinline__ void gl_lds16(const unsigned short* g, unsigned short* l) {
  __builtin_amdgcn_global_load_lds(
      (const __attribute__((address_space(1))) void*)(g),
      (__attribute__((address_space(3))) void*)(l), 16, 0, 0);
}

// ---------------- fused fp32 -> bf16 conversion (3 tensors, 1 launch) ----------------
__global__ __launch_bounds__(256) void cvt3_kernel(
    const float* __restrict__ a, unsigned short* __restrict__ oa, int na4,
    const float* __restrict__ b, unsigned short* __restrict__ ob, int nb4,
    const float* __restrict__ c, unsigned short* __restrict__ oc, int nc4)
{
  int i = blockIdx.x * 256 + threadIdx.x;
  const float* src; unsigned short* dst; int j;
  if (i < na4) { src = a; dst = oa; j = i; }
  else if (i < na4 + nb4) { src = b; dst = ob; j = i - na4; }
  else if (i < na4 + nb4 + nc4) { src = c; dst = oc; j = i - na4 - nb4; }
  else return;
  float4 v = ((const float4*)src)[j];
  ushort4 o;
  o.x = f2b(v.x); o.y = f2b(v.y); o.z = f2b(v.z); o.w = f2b(v.w);
  ((ushort4*)dst)[j] = o;
}

// ---------------- bf16 GEMM: C[m][n] = sum_k A[m][k] * Bt[n][k] ----------------
// m97 structure: global_load_lds width=16 staging, unpadded LDS, XOR chunk swizzle.
// Tile: 128 x TN (TN in {64,128,256}). 4 waves: wm=wave&1 (m-half), wn=wave>>1 (n-half).
template<int TN, int OUT_BF16>
__global__ __launch_bounds__(256) void gemm_bt(
    const unsigned short* __restrict__ A, const unsigned short* __restrict__ Bt,
    void* __restrict__ Cout, int M, int N, int K, int ldc)
{
  constexpr int NT = TN / 32;                 // n-tiles per wave
  const int bm = blockIdx.x, bn = blockIdx.y;
  const int tid = threadIdx.x;
  const int wave = tid >> 6, lane = tid & 63;
  const int wm = wave & 1, wn = wave >> 1;
  const int q = lane >> 4, lr = lane & 15;

  __shared__ __align__(16) unsigned short As[128 * 64];
  __shared__ __align__(16) unsigned short Bs[TN * 64];

  v4f acc[4][NT];
#pragma unroll
  for (int i = 0; i < 4; i++)
#pragma unroll
    for (int j = 0; j < NT; j++) acc[i][j] = v4f{0.f, 0.f, 0.f, 0.f};

  const int lrow = lane >> 3;                 // 0..7 (row within 8-row group)
  const int gchunk = (lane & 7) ^ lrow;       // swizzled source 16B-chunk

  for (int k0 = 0; k0 < K; k0 += 64) {
    __syncthreads();
#pragma unroll
    for (int it = 0; it < 4; ++it) {
      int r = wave * 32 + it * 8 + lrow;
      gl_lds16(A + (size_t)(bm * 128 + r) * K + k0 + gchunk * 8,
               &As[(wave * 32 + it * 8) * 64]);
    }
#pragma unroll
    for (int it = 0; it < TN / 32; ++it) {
      int rloc = wave * (TN / 4) + it * 8;
      int rb = bn * TN + rloc + lrow; if (rb >= N) rb = N - 1;  // clamp; junk never stored
      gl_lds16(Bt + (size_t)rb * K + k0 + gchunk * 8, &Bs[rloc * 64]);
    }
    __syncthreads();
#pragma unroll
    for (int ks = 0; ks < 64; ks += 32) {
      const int c0 = (ks >> 3) + q;           // 16B-chunk index 0..7
      v8s af[4], bf[NT];
#pragma unroll
      for (int mt = 0; mt < 4; ++mt) {
        int r = wm * 64 + mt * 16 + lr;
        af[mt] = *(const v8s*)&As[r * 64 + ((c0 ^ (r & 7)) << 3)];
      }
#pragma unroll
      for (int nt = 0; nt < NT; ++nt) {
        int r = wn * (TN / 2) + nt * 16 + lr;
        bf[nt] = *(const v8s*)&Bs[r * 64 + ((c0 ^ (r & 7)) << 3)];
      }
#pragma unroll
      for (int mt = 0; mt < 4; ++mt)
#pragma unroll
        for (int nt = 0; nt < NT; ++nt)
          acc[mt][nt] = mfma16(af[mt], bf[nt], acc[mt][nt]);
    }
  }
#pragma unroll
  for (int mt = 0; mt < 4; ++mt) {
#pragma unroll
    for (int nt = 0; nt < NT; ++nt) {
      int row = bm * 128 + wm * 64 + mt * 16 + q * 4;
      int col = bn * TN + wn * (TN / 2) + nt * 16 + lr;
      if (col < N) {
#pragma unroll
        for (int r = 0; r < 4; ++r) {
          float v = acc[mt][nt][r];
          if (OUT_BF16) ((unsigned short*)Cout)[(size_t)(row + r) * ldc + col] = f2b(v);
          else          ((float*)Cout)[(size_t)(row + r) * ldc + col] = v;
        }
      }
    }
  }
}

// ---------------- tree conv + SiLU + dt softplus (vectorized) ----------------
__global__ __launch_bounds__(256) void conv_kernel(
    const unsigned short* __restrict__ C1, const int* __restrict__ cidx,
    const float* __restrict__ convw, const float* __restrict__ convb,
    const float* __restrict__ dtbias,
    unsigned short* __restrict__ x16, unsigned short* __restrict__ Bg16,
    unsigned short* __restrict__ Cg16, float* __restrict__ dtb)
{
  int bl = blockIdx.x;                 // b*2048 + l
  int b = bl >> 11;
  int tid = threadIdx.x;
  __shared__ int idxs[4];
  if (tid < 4) idxs[tid] = cidx[b * (4 * LL) + ((bl & 2047) * 4) + tid];
  __syncthreads();
  const unsigned short* rows[4];
#pragma unroll
  for (int k = 0; k < 4; k++) {
    int iv = idxs[k];
    rows[k] = (iv > 0) ? (C1 + (size_t)(b * LL + iv - 1) * DPROJ + DSSM) : (const unsigned short*)0;
  }
  const float4* cw4 = (const float4*)convw;
#pragma unroll
  for (int it = 0; it < 3; ++it) {
    int unit = tid + it * 256;         // 0..575 (4-col groups)
    if (unit >= CONVD / 4) break;
    int c4 = unit * 4;
    ushort4 rv[4];
#pragma unroll
    for (int k = 0; k < 4; ++k)
      rv[k] = rows[k] ? *(const ushort4*)(rows[k] + c4) : make_ushort4(0, 0, 0, 0);
    float4 w0 = cw4[c4], w1 = cw4[c4 + 1], w2 = cw4[c4 + 2], w3 = cw4[c4 + 3];
    float4 cb = *(const float4*)(convb + c4);
    float a0 = cb.x + b2f(rv[0].x) * w0.x + b2f(rv[1].x) * w0.y + b2f(rv[2].x) * w0.z + b2f(rv[3].x) * w0.w;
    float a1 = cb.y + b2f(rv[0].y) * w1.x + b2f(rv[1].y) * w1.y + b2f(rv[2].y) * w1.z + b2f(rv[3].y) * w1.w;
    float a2 = cb.z + b2f(rv[0].z) * w2.x + b2f(rv[1].z) * w2.y + b2f(rv[2].z) * w2.z + b2f(rv[3].z) * w2.w;
    float a3 = cb.w + b2f(rv[0].w) * w3.x + b2f(rv[1].w) * w3.y + b2f(rv[2].w) * w3.z + b2f(rv[3].w) * w3.w;
    ushort4 o;
    o.x = f2b(a0 / (1.f + __expf(-a0)));
    o.y = f2b(a1 / (1.f + __expf(-a1)));
    o.z = f2b(a2 / (1.f + __expf(-a2)));
    o.w = f2b(a3 / (1.f + __expf(-a3)));
    if (c4 < DSSM)            *(ushort4*)(x16 + (size_t)bl * DSSM + c4) = o;
    else if (c4 < DSSM + DST) *(ushort4*)(Bg16 + (size_t)bl * DST + (c4 - DSSM)) = o;
    else                      *(ushort4*)(Cg16 + (size_t)bl * DST + (c4 - DSSM - DST)) = o;
  }
  if (tid < NH) {
    float raw = b2f(C1[(size_t)bl * DPROJ + DSSM + CONVD + tid]) + dtbias[tid];
    float dtv = (raw > 20.f) ? raw : log1pf(__expf(raw));
    dtb[(size_t)bl * NH + tid] = dtv;
  }
}

// ---------------- SSD intra-chunk: Yd, per-chunk states^T, decays ----------------
// 4 barriers; wave0 shfl-scan; states stored TRANSPOSED [p][n] (A=xT, B=BTw role swap)
__global__ __launch_bounds__(256) void d1_intra(
    const unsigned short* __restrict__ x16, const unsigned short* __restrict__ Bg16,
    const unsigned short* __restrict__ Cg16, const float* __restrict__ dtb,
    const float* __restrict__ A_log,
    unsigned short* __restrict__ y16, unsigned short* __restrict__ statesb,
    float* __restrict__ cdb, float* __restrict__ acumb)
{
  int gid = blockIdx.x;
  int h = gid & 31, ci = (gid >> 5) & 31, b = gid >> 10;
  int tid = threadIdx.x, wave = tid >> 6, lane = tid & 63, q = lane >> 4, lr = lane & 15;

  __shared__ __align__(16) unsigned short BnG[CS * 136];  // B[s][n]; reused as G[t][s] (stride 72)
  __shared__ __align__(16) unsigned short BTw[DST * 72];  // B^T[n][s] * dec[s] * dt[s]
  __shared__ __align__(16) unsigned short xT[HD * 72];    // x^T[p][s]  (no dt)
  __shared__ float dt_s[CS], ac_s[CS], dec_s[CS];

  const size_t blbase = (size_t)b * LL + ci * CS;
  const size_t chbase = (size_t)(b * NC + ci) * NH + h;
  float Ah = -__expf(A_log[h]);

  // wave0: dt load + shuffle inclusive scan (no barriers)
  if (wave == 0) {
    float d = dtb[(blbase + lane) * NH + h];
    float a = d * Ah;
#pragma unroll
    for (int off = 1; off < 64; off <<= 1) {
      float u = __shfl_up(a, off, 64);
      if (lane >= off) a += u;
    }
    float tot = __shfl(a, 63, 64);
    dt_s[lane] = d;
    ac_s[lane] = a;
    dec_s[lane] = __expf(tot - a);
    acumb[chbase * CS + lane] = a;
    if (lane == 0) cdb[chbase] = __expf(tot);
  }

  // stage B tile (64 x 128) and x^T (64p x 64s)
#pragma unroll
  for (int g = 0; g < 8; ++g) {
    int f = g * 256 + tid;              // s(64) x n-quads(32)
    int s = f >> 5, c4 = (f & 31) * 4;
    *(ushort4*)&BnG[s * 136 + c4] = *(const ushort4*)(Bg16 + (blbase + s) * DST + c4);
  }
#pragma unroll
  for (int g = 0; g < 4; ++g) {
    int f = g * 256 + tid;              // s(64) x p-quads(16)
    int s = f >> 4, p4 = (f & 15) * 4;
    ushort4 xv = *(const ushort4*)(x16 + (blbase + s) * DSSM + h * HD + p4);
    xT[(p4 + 0) * 72 + s] = xv.x;
    xT[(p4 + 1) * 72 + s] = xv.y;
    xT[(p4 + 2) * 72 + s] = xv.z;
    xT[(p4 + 3) * 72 + s] = xv.w;
  }
  __syncthreads();                      // barrier 1

  // BTw[n][s] = B[s][n] * dec[s] * dt[s]
#pragma unroll
  for (int g = 0; g < 4; ++g) {
    int f = g * 256 + tid;              // n(128) x sg(8)
    int n = f >> 3, sg = f & 7;
    int s0 = sg * 8;
    ushort4 lo, hi;
    lo.x = f2b(b2f(BnG[(s0 + 0) * 136 + n]) * dec_s[s0 + 0] * dt_s[s0 + 0]);
    lo.y = f2b(b2f(BnG[(s0 + 1) * 136 + n]) * dec_s[s0 + 1] * dt_s[s0 + 1]);
    lo.z = f2b(b2f(BnG[(s0 + 2) * 136 + n]) * dec_s[s0 + 2] * dt_s[s0 + 2]);
    lo.w = f2b(b2f(BnG[(s0 + 3) * 136 + n]) * dec_s[s0 + 3] * dt_s[s0 + 3]);
    hi.x = f2b(b2f(BnG[(s0 + 4) * 136 + n]) * dec_s[s0 + 4] * dt_s[s0 + 4]);
    hi.y = f2b(b2f(BnG[(s0 + 5) * 136 + n]) * dec_s[s0 + 5] * dt_s[s0 + 5]);
    hi.z = f2b(b2f(BnG[(s0 + 6) * 136 + n]) * dec_s[s0 + 6] * dt_s[s0 + 6]);
    hi.w = f2b(b2f(BnG[(s0 + 7) * 136 + n]) * dec_s[s0 + 7] * dt_s[s0 + 7]);
    *(ushort4*)&BTw[n * 72 + s0] = lo;
    *(ushort4*)&BTw[n * 72 + s0 + 4] = hi;
  }

  // S[t][s] = sum_n C[t][n] * B[s][n]  (C A-fragments direct from global)
  v4f accS[4];
#pragma unroll
  for (int i = 0; i < 4; i++) accS[i] = v4f{0.f, 0.f, 0.f, 0.f};
#pragma unroll
  for (int ks = 0; ks < 128; ks += 32) {
    v8s a = *(const v8s*)(Cg16 + (blbase + wave * 16 + lr) * DST + ks + q * 8);
#pragma unroll
    for (int si = 0; si < 4; ++si) {
      v8s bb = *(const v8s*)&BnG[(si * 16 + lr) * 136 + ks + q * 8];
      accS[si] = mfma16(a, bb, accS[si]);
    }
  }
  __syncthreads();                      // barrier 2 (BnG reads done)

  // G[t][s] = S * exp(Acum[t]-Acum[s]) * dt[s], masked s<=t; stride 72
  {
    int tbase = wave * 16 + q * 4;
#pragma unroll
    for (int si = 0; si < 4; ++si) {
      int s = si * 16 + lr;
      float ds = dt_s[s], as = ac_s[s];
#pragma unroll
      for (int r = 0; r < 4; ++r) {
        int tt = tbase + r;
        float g = 0.f;
        if (s <= tt) g = accS[si][r] * __expf(ac_s[tt] - as) * ds;
        BnG[tt * 72 + s] = f2b(g);
      }
    }
  }
  __syncthreads();                      // barrier 3

  // Yd[t][p] = G @ x ; states^T[p][n] = sum_s xT[p][s]*BTw[n][s]
  // xf[] doubles as accY's B-operand and accPT's A-operand (identical reads)
  v4f accY[4], accPT[4][2];
#pragma unroll
  for (int i = 0; i < 4; i++) {
    accY[i] = v4f{0.f,0.f,0.f,0.f};
    accPT[i][0] = v4f{0.f,0.f,0.f,0.f};
    accPT[i][1] = v4f{0.f,0.f,0.f,0.f};
  }
  int nw = wave * 32;                   // wave covers n in [nw, nw+32)
#pragma unroll
  for (int ks = 0; ks < 64; ks += 32) {
    v8s xf[4];
#pragma unroll
    for (int i = 0; i < 4; ++i) xf[i] = *(const v8s*)&xT[(i * 16 + lr) * 72 + ks + q * 8];
    v8s aG  = *(const v8s*)&BnG[(wave * 16 + lr) * 72 + ks + q * 8];
    v8s bw0 = *(const v8s*)&BTw[(nw + lr) * 72 + ks + q * 8];
    v8s bw1 = *(const v8s*)&BTw[(nw + 16 + lr) * 72 + ks + q * 8];
#pragma unroll
    for (int nt = 0; nt < 4; ++nt) {
      accY[nt] = mfma16(aG, xf[nt], accY[nt]);
      accPT[nt][0] = mfma16(xf[nt], bw0, accPT[nt][0]);
      accPT[nt][1] = mfma16(xf[nt], bw1, accPT[nt][1]);
    }
  }

  // epilogue: Yd
#pragma unroll
  for (int nt = 0; nt < 4; ++nt) {
    int p = nt * 16 + lr;
#pragma unroll
    for (int r = 0; r < 4; ++r) {
      int t = wave * 16 + q * 4 + r;
      y16[(blbase + t) * DSSM + h * HD + p] = f2b(accY[nt][r]);
    }
  }
  // epilogue: states^T  (layout [p][n], p<HD rows, n<DST cols)
  size_t sbase = chbase * (DST * HD);
#pragma unroll
  for (int mt = 0; mt < 4; ++mt) {
#pragma unroll
    for (int nt = 0; nt < 2; ++nt) {
      int n = nw + nt * 16 + lr;
#pragma unroll
      for (int r = 0; r < 4; ++r) {
        int p = mt * 16 + q * 4 + r;
        statesb[sbase + (size_t)p * DST + n] = f2b(accPT[mt][nt][r]);
      }
    }
  }
}

// ---------------- state passing: all loads upfront, register scan ----------------
// 2048 blocks: (b,h) x 32 segments of the 8192-elem state; 1 elem/thread over 32 chunks
__global__ __launch_bounds__(256) void d2_scan(
    unsigned short* __restrict__ statesb, const float* __restrict__ cdb)
{
  int g = blockIdx.x;
  int seg = g & 31, bh = g >> 5;
  int b = bh >> 5, h = bh & 31;
  int e = seg * 256 + threadIdx.x;      // 0..8191
  const size_t cstride = (size_t)NH * DST * HD;
  size_t base = ((size_t)(b * NC) * NH + h) * (DST * HD) + e;
  unsigned short st[NC];
#pragma unroll
  for (int ci = 0; ci < NC; ++ci) st[ci] = statesb[base + ci * cstride];
  float run = 0.f;
#pragma unroll
  for (int ci = 0; ci < NC; ++ci) {
    float cd = cdb[(b * NC + ci) * NH + h];
    statesb[base + ci * cstride] = f2b(run);   // prev entering chunk ci
    run = run * cd + b2f(st[ci]);
  }
}

// ---------------- SSD inter-chunk: Y += exp(Acum[t]) * C @ prev^T + D*x ----------------
// prev stored [p][n] -> straight vector staging, no transpose
__global__ __launch_bounds__(256) void d3_inter(
    const unsigned short* __restrict__ x16, const unsigned short* __restrict__ Cg16,
    const unsigned short* __restrict__ statesb, const float* __restrict__ acumb,
    const float* __restrict__ Dp, unsigned short* __restrict__ y16)
{
  int gid = blockIdx.x;
  int h = gid & 31, ci = (gid >> 5) & 31, b = gid >> 10;
  int tid = threadIdx.x, wave = tid >> 6, lane = tid & 63, q = lane >> 4, lr = lane & 15;
  __shared__ __align__(16) unsigned short pT[HD * 136];   // prev^T[p][n]
  __shared__ __align__(16) float ys[CS * 68];             // y-stage (fp32)
  __shared__ float ea[CS];
  const size_t blbase = (size_t)b * LL + ci * CS;
  const size_t chbase = (size_t)(b * NC + ci) * NH + h;
  if (tid < CS) ea[tid] = __expf(acumb[chbase * CS + tid]);
  size_t sbase = chbase * (DST * HD);
  // stage prev^T: plain vector copy (64 rows x 128 cols)
#pragma unroll
  for (int g = 0; g < 8; ++g) {
    int f = g * 256 + tid;              // p(64) x n-quads(32)
    int p = f >> 5, c4 = (f & 31) * 4;
    *(ushort4*)&pT[p * 136 + c4] = *(const ushort4*)(statesb + sbase + (size_t)p * DST + c4);
  }
  __syncthreads();
  v4f acc[4];
#pragma unroll
  for (int i = 0; i < 4; i++) acc[i] = v4f{0.f, 0.f, 0.f, 0.f};
#pragma unroll
  for (int ks = 0; ks < 128; ks += 32) {
    v8s a = *(const v8s*)(Cg16 + (blbase + wave * 16 + lr) * DST + ks + q * 8);
#pragma unroll
    for (int nt = 0; nt < 4; ++nt) {
      v8s bb = *(const v8s*)&pT[(nt * 16 + lr) * 136 + ks + q * 8];
      acc[nt] = mfma16(a, bb, acc[nt]);
    }
  }
  // stage Yoff to LDS (fp32), then vectorized RMW epilogue
#pragma unroll
  for (int nt = 0; nt < 4; ++nt) {
#pragma unroll
    for (int r = 0; r < 4; ++r)
      ys[(wave * 16 + q * 4 + r) * 68 + nt * 16 + lr] = acc[nt][r];
  }
  __syncthreads();
  float Dh = Dp[h];
#pragma unroll
  for (int it = 0; it < 2; ++it) {
    int unit = it * 256 + tid;          // t(64) x p8(8)
    int t = unit >> 3, p8 = (unit & 7) * 8;
    float ea_t = ea[t];
    size_t off = (blbase + t) * DSSM + h * HD + p8;
    uint4 yv = *(const uint4*)(y16 + off);
    uint4 xv = *(const uint4*)(x16 + off);
    float4 o0 = *(const float4*)&ys[t * 68 + p8];
    float4 o1 = *(const float4*)&ys[t * 68 + p8 + 4];
    const unsigned int* yu = (const unsigned int*)&yv;
    const unsigned int* xu = (const unsigned int*)&xv;
    float oo[8] = {o0.x, o0.y, o0.z, o0.w, o1.x, o1.y, o1.z, o1.w};
    unsigned int ro[4];
#pragma unroll
    for (int d = 0; d < 4; ++d) {
      unsigned short y0 = (unsigned short)(yu[d] & 0xffffu), y1 = (unsigned short)(yu[d] >> 16);
      unsigned short x0 = (unsigned short)(xu[d] & 0xffffu), x1 = (unsigned short)(xu[d] >> 16);
      float v0 = b2f(y0) + ea_t * oo[d * 2 + 0] + Dh * b2f(x0);
      float v1 = b2f(y1) + ea_t * oo[d * 2 + 1] + Dh * b2f(x1);
      ro[d] = (unsigned int)f2b(v0) | ((unsigned int)f2b(v1) << 16);
    }
    *(uint4*)(y16 + off) = make_uint4(ro[0], ro[1], ro[2], ro[3]);
  }
}

// ---------------- gated RMSNorm (vectorized) ----------------
__global__ __launch_bounds__(256) void norm_kernel(
    const unsigned short* __restrict__ y16, const unsigned short* __restrict__ C1,
    const float* __restrict__ normw, unsigned short* __restrict__ yzn)
{
  int bl = blockIdx.x;
  int tid = threadIdx.x;
  int wave = tid >> 6, lane = tid & 63;
  int c8 = tid * 8;
  uint4 yv = *(const uint4*)(y16 + (size_t)bl * DSSM + c8);
  uint4 zv = *(const uint4*)(C1 + (size_t)bl * DPROJ + c8);   // z = first 2048 cols
  const unsigned int* yu = (const unsigned int*)&yv;
  const unsigned int* zu = (const unsigned int*)&zv;
  float vals[8];
  float ss = 0.f;
#pragma unroll
  for (int d = 0; d < 4; ++d) {
    unsigned short y0 = (unsigned short)(yu[d] & 0xffffu), y1 = (unsigned short)(yu[d] >> 16);
    unsigned short z0 = (unsigned short)(zu[d] & 0xffffu), z1 = (unsigned short)(zu[d] >> 16);
    float zf0 = b2f(z0), zf1 = b2f(z1);
    float v0 = b2f(y0) * (zf0 / (1.f + __expf(-zf0)));
    float v1 = b2f(y1) * (zf1 / (1.f + __expf(-zf1)));
    vals[d * 2] = v0; vals[d * 2 + 1] = v1;
    ss += v0 * v0 + v1 * v1;
  }
#pragma unroll
  for (int off = 32; off > 0; off >>= 1) ss += __shfl_down(ss, off);
  __shared__ float red[4];
  if (lane == 0) red[wave] = ss;
  __syncthreads();
  float tot = red[0] + red[1] + red[2] + red[3];
  float scale = rsqrtf(tot * (1.f / 2048.f) + 1e-5f);
  float4 w0 = *(const float4*)(normw + c8);
  float4 w1 = *(const float4*)(normw + c8 + 4);
  float ws[8] = {w0.x, w0.y, w0.z, w0.w, w1.x, w1.y, w1.z, w1.w};
  unsigned int ro[4];
#pragma unroll
  for (int d = 0; d < 4; ++d) {
    unsigned short r0 = f2b(vals[d * 2] * scale * ws[d * 2]);
    unsigned short r1 = f2b(vals[d * 2 + 1] * scale * ws[d * 2 + 1]);
    ro[d] = (unsigned int)r0 | ((unsigned int)r1 << 16);
  }
  *(uint4*)(yzn + (size_t)bl * DSSM + c8) = make_uint4(ro[0], ro[1], ro[2], ro[3]);
}

// ---------------- host launch ----------------
extern "C" void kernel_launch(void* const* d_in, const int* in_sizes, int n_in,
                              void* d_out, int out_size, void* d_ws, size_t ws_size,
                              hipStream_t stream) {
  const float* u      = (const float*)d_in[0];
  const int*   cidx   = (const int*)d_in[1];
  const float* W_in   = (const float*)d_in[2];
  const float* convw  = (const float*)d_in[3];
  const float* convb  = (const float*)d_in[4];
  const float* dtbias = (const float*)d_in[5];
  const float* A_log  = (const float*)d_in[6];
  const float* Dp     = (const float*)d_in[7];
  const float* normw  = (const float*)d_in[8];
  const float* W_out  = (const float*)d_in[9];

  char* w = (char*)d_ws;
  size_t off = 0;
  auto alloc = [&](size_t bytes) { char* p = w + off; off += (bytes + 255) & ~(size_t)255; return p; };
  unsigned short* u16     = (unsigned short*)alloc((size_t)BLTOT * DMODEL * 2);
  unsigned short* Win16   = (unsigned short*)alloc((size_t)DPROJ * DMODEL * 2);
  unsigned short* Wout16  = (unsigned short*)alloc((size_t)DMODEL * DSSM * 2);
  unsigned short* C1      = (unsigned short*)alloc((size_t)BLTOT * DPROJ * 2);
  unsigned short* x16     = (unsigned short*)alloc((size_t)BLTOT * DSSM * 2);
  unsigned short* Bg16    = (unsigned short*)alloc((size_t)BLTOT * DST * 2);
  unsigned short* Cg16    = (unsigned short*)alloc((size_t)BLTOT * DST * 2);
  float*          dtb     = (float*)alloc((size_t)BLTOT * NH * 4);
  float*          acumb   = (float*)alloc((size_t)BB * NC * NH * CS * 4);
  unsigned short* y16     = (unsigned short*)alloc((size_t)BLTOT * DSSM * 2);
  unsigned short* statesb = (unsigned short*)alloc((size_t)BB * NC * NH * DST * HD * 2);
  float*          cdb     = (float*)alloc((size_t)BB * NC * NH * 4);
  unsigned short* yzn     = (unsigned short*)alloc((size_t)BLTOT * DSSM * 2);

  const int na4 = BLTOT * DMODEL / 4, nb4 = DPROJ * DMODEL / 4, nc4 = DMODEL * DSSM / 4;
  cvt3_kernel<<<(na4 + nb4 + nc4 + 255) / 256, 256, 0, stream>>>(
      u, u16, na4, W_in, Win16, nb4, W_out, Wout16, nc4);

  // zxbcdt = u @ W_in^T   (bf16 out, ld 4384) — 128x256 tiles (dual B-tile)
  gemm_bt<256, 1><<<dim3(BLTOT / 128, (DPROJ + 255) / 256), 256, 0, stream>>>(
      u16, Win16, C1, BLTOT, DPROJ, DMODEL, DPROJ);
  conv_kernel<<<BLTOT, 256, 0, stream>>>(C1, cidx, convw, convb, dtbias, x16, Bg16, Cg16, dtb);
  d1_intra<<<BB * NC * NH, 256, 0, stream>>>(x16, Bg16, Cg16, dtb, A_log, y16, statesb, cdb, acumb);
  d2_scan<<<BB * NH * 32, 256, 0, stream>>>(statesb, cdb);
  d3_inter<<<BB * NC * NH, 256, 0, stream>>>(x16, Cg16, statesb, acumb, Dp, y16);
  norm_kernel<<<BLTOT, 256, 0, stream>>>(y16, C1, normw, yzn);
  // out = yzn @ W_out^T   (fp32 out) — 128x64 tiles for 512 blocks (2+/CU)
  gemm_bt<64, 0><<<dim3(BLTOT / 128, DMODEL / 64), 256, 0, stream>>>(
      yzn, Wout16, (float*)d_out, BLTOT, DMODEL, DSSM, DMODEL);
}

// Round 6
// 271.356 us; speedup vs baseline: 1.1163x; 1.1163x over previous
//
#include <hip/hip_runtime.h>

// ---- problem constants ----
#define BB 2
#define LL 2048
#define DMODEL 1024
#define DSSM 2048
#define NH 32
#define HD 64
#define DST 128
#define CONVD 2304
#define DPROJ 4384
#define CS 64               // SSD chunk size (rechunked; math is exact)
#define NC 32               // LL/CS
#define BLTOT (BB*LL)       // 4096

typedef short v8s __attribute__((ext_vector_type(8)));
typedef float v4f __attribute__((ext_vector_type(4)));

__device__ __forceinline__ float b2f(unsigned short h) {
  union { unsigned int u; float f; } v; v.u = ((unsigned int)h) << 16; return v.f;
}
__device__ __forceinline__ unsigned short f2b(float f) {
  union { float f; unsigned int u; } v; v.f = f;
  unsigned int u = v.u;
  return (unsigned short)((u + 0x7fffu + ((u >> 16) & 1u)) >> 16);
}
__device__ __forceinline__ v4f mfma16(v8s a, v8s b, v4f c) {
  return __builtin_amdgcn_mfma_f32_16x16x32_bf16(a, b, c, 0, 0, 0);
}
// async global->LDS, 16B per lane; LDS dest = wave-uniform base + lane*16
__device__ __forceinline__ void gl_lds16(const unsigned short* g, unsigned short* l) {
  __builtin_amdgcn_global_load_lds(
      (const __attribute__((address_space(1))) void*)(g),
      (__attribute__((address_space(3))) void*)(l), 16, 0, 0);
}

// ---------------- fused fp32 -> bf16 conversion (3 tensors, 1 launch) ----------------
__global__ __launch_bounds__(256) void cvt3_kernel(
    const float* __restrict__ a, unsigned short* __restrict__ oa, int na4,
    const float* __restrict__ b, unsigned short* __restrict__ ob, int nb4,
    const float* __restrict__ c, unsigned short* __restrict__ oc, int nc4)
{
  int i = blockIdx.x * 256 + threadIdx.x;
  const float* src; unsigned short* dst; int j;
  if (i < na4) { src = a; dst = oa; j = i; }
  else if (i < na4 + nb4) { src = b; dst = ob; j = i - na4; }
  else if (i < na4 + nb4 + nc4) { src = c; dst = oc; j = i - na4 - nb4; }
  else return;
  float4 v = ((const float4*)src)[j];
  ushort4 o;
  o.x = f2b(v.x); o.y = f2b(v.y); o.z = f2b(v.z); o.w = f2b(v.w);
  ((ushort4*)dst)[j] = o;
}

// ---------------- 256x128-tile bf16 GEMM, 512 threads / 8 waves ----------------
// C[m][n] = sum_k A[m][k] * Bt[n][k]. Each wave owns 64x64 (acc[4][4] = 64 VGPR).
// m97 staging: global_load_lds width=16, unpadded LDS, XOR chunk swizzle.
__global__ __launch_bounds__(512) void gemm_big(
    const unsigned short* __restrict__ A, const unsigned short* __restrict__ Bt,
    unsigned short* __restrict__ Cout, int M, int N, int K, int ldc)
{
  const int bm = blockIdx.x, bn = blockIdx.y;
  const int tid = threadIdx.x;
  const int wave = tid >> 6, lane = tid & 63;
  const int wm = wave & 3, wn = wave >> 2;    // m-quarter (64), n-half (64)
  const int q = lane >> 4, lr = lane & 15;

  __shared__ __align__(16) unsigned short As[256 * 64];   // 32 KB
  __shared__ __align__(16) unsigned short Bs[128 * 64];   // 16 KB

  v4f acc[4][4];
#pragma unroll
  for (int i = 0; i < 4; i++)
#pragma unroll
    for (int j = 0; j < 4; j++) acc[i][j] = v4f{0.f, 0.f, 0.f, 0.f};

  const int lrow = lane >> 3;                 // 0..7 (row within 8-row group)
  const int gchunk = (lane & 7) ^ lrow;       // swizzled source 16B-chunk

  for (int k0 = 0; k0 < K; k0 += 64) {
    __syncthreads();
#pragma unroll
    for (int it = 0; it < 4; ++it) {          // A: 256 rows, 32/wave
      int r = wave * 32 + it * 8 + lrow;
      gl_lds16(A + (size_t)(bm * 256 + r) * K + k0 + gchunk * 8,
               &As[(wave * 32 + it * 8) * 64]);
    }
#pragma unroll
    for (int it = 0; it < 2; ++it) {          // B: 128 rows, 16/wave
      int rloc = wave * 16 + it * 8;
      int rb = bn * 128 + rloc + lrow; if (rb >= N) rb = N - 1;  // clamp; junk never stored
      gl_lds16(Bt + (size_t)rb * K + k0 + gchunk * 8, &Bs[rloc * 64]);
    }
    __syncthreads();
#pragma unroll
    for (int ks = 0; ks < 64; ks += 32) {
      const int c0 = (ks >> 3) + q;           // 16B-chunk index 0..7
      v8s af[4], bf[4];
#pragma unroll
      for (int mt = 0; mt < 4; ++mt) {
        int r = wm * 64 + mt * 16 + lr;
        af[mt] = *(const v8s*)&As[r * 64 + ((c0 ^ (r & 7)) << 3)];
      }
#pragma unroll
      for (int nt = 0; nt < 4; ++nt) {
        int r = wn * 64 + nt * 16 + lr;
        bf[nt] = *(const v8s*)&Bs[r * 64 + ((c0 ^ (r & 7)) << 3)];
      }
#pragma unroll
      for (int mt = 0; mt < 4; ++mt)
#pragma unroll
        for (int nt = 0; nt < 4; ++nt)
          acc[mt][nt] = mfma16(af[mt], bf[nt], acc[mt][nt]);
    }
  }
#pragma unroll
  for (int mt = 0; mt < 4; ++mt) {
#pragma unroll
    for (int nt = 0; nt < 4; ++nt) {
      int row = bm * 256 + wm * 64 + mt * 16 + q * 4;
      int col = bn * 128 + wn * 64 + nt * 16 + lr;
      if (col < N) {
#pragma unroll
        for (int r = 0; r < 4; ++r)
          Cout[(size_t)(row + r) * ldc + col] = f2b(acc[mt][nt][r]);
      }
    }
  }
}

// ---------------- bf16 GEMM: 128 x TN tile, 256 threads (gemm2) ----------------
template<int TN, int OUT_BF16>
__global__ __launch_bounds__(256) void gemm_bt(
    const unsigned short* __restrict__ A, const unsigned short* __restrict__ Bt,
    void* __restrict__ Cout, int M, int N, int K, int ldc)
{
  constexpr int NT = TN / 32;                 // n-tiles per wave
  const int bm = blockIdx.x, bn = blockIdx.y;
  const int tid = threadIdx.x;
  const int wave = tid >> 6, lane = tid & 63;
  const int wm = wave & 1, wn = wave >> 1;
  const int q = lane >> 4, lr = lane & 15;

  __shared__ __align__(16) unsigned short As[128 * 64];
  __shared__ __align__(16) unsigned short Bs[TN * 64];

  v4f acc[4][NT];
#pragma unroll
  for (int i = 0; i < 4; i++)
#pragma unroll
    for (int j = 0; j < NT; j++) acc[i][j] = v4f{0.f, 0.f, 0.f, 0.f};

  const int lrow = lane >> 3;                 // 0..7 (row within 8-row group)
  const int gchunk = (lane & 7) ^ lrow;       // swizzled source 16B-chunk

  for (int k0 = 0; k0 < K; k0 += 64) {
    __syncthreads();
#pragma unroll
    for (int it = 0; it < 4; ++it) {
      int r = wave * 32 + it * 8 + lrow;
      gl_lds16(A + (size_t)(bm * 128 + r) * K + k0 + gchunk * 8,
               &As[(wave * 32 + it * 8) * 64]);
    }
#pragma unroll
    for (int it = 0; it < TN / 32; ++it) {
      int rloc = wave * (TN / 4) + it * 8;
      int rb = bn * TN + rloc + lrow; if (rb >= N) rb = N - 1;  // clamp; junk never stored
      gl_lds16(Bt + (size_t)rb * K + k0 + gchunk * 8, &Bs[rloc * 64]);
    }
    __syncthreads();
#pragma unroll
    for (int ks = 0; ks < 64; ks += 32) {
      const int c0 = (ks >> 3) + q;           // 16B-chunk index 0..7
      v8s af[4], bf[NT];
#pragma unroll
      for (int mt = 0; mt < 4; ++mt) {
        int r = wm * 64 + mt * 16 + lr;
        af[mt] = *(const v8s*)&As[r * 64 + ((c0 ^ (r & 7)) << 3)];
      }
#pragma unroll
      for (int nt = 0; nt < NT; ++nt) {
        int r = wn * (TN / 2) + nt * 16 + lr;
        bf[nt] = *(const v8s*)&Bs[r * 64 + ((c0 ^ (r & 7)) << 3)];
      }
#pragma unroll
      for (int mt = 0; mt < 4; ++mt)
#pragma unroll
        for (int nt = 0; nt < NT; ++nt)
          acc[mt][nt] = mfma16(af[mt], bf[nt], acc[mt][nt]);
    }
  }
#pragma unroll
  for (int mt = 0; mt < 4; ++mt) {
#pragma unroll
    for (int nt = 0; nt < NT; ++nt) {
      int row = bm * 128 + wm * 64 + mt * 16 + q * 4;
      int col = bn * TN + wn * (TN / 2) + nt * 16 + lr;
      if (col < N) {
#pragma unroll
        for (int r = 0; r < 4; ++r) {
          float v = acc[mt][nt][r];
          if (OUT_BF16) ((unsigned short*)Cout)[(size_t)(row + r) * ldc + col] = f2b(v);
          else          ((float*)Cout)[(size_t)(row + r) * ldc + col] = v;
        }
      }
    }
  }
}

// ---------------- tree conv + SiLU + dt softplus (vectorized) ----------------
__global__ __launch_bounds__(256) void conv_kernel(
    const unsigned short* __restrict__ C1, const int* __restrict__ cidx,
    const float* __restrict__ convw, const float* __restrict__ convb,
    const float* __restrict__ dtbias,
    unsigned short* __restrict__ x16, unsigned short* __restrict__ Bg16,
    unsigned short* __restrict__ Cg16, float* __restrict__ dtb)
{
  int bl = blockIdx.x;                 // b*2048 + l
  int b = bl >> 11;
  int tid = threadIdx.x;
  __shared__ int idxs[4];
  if (tid < 4) idxs[tid] = cidx[b * (4 * LL) + ((bl & 2047) * 4) + tid];
  __syncthreads();
  const unsigned short* rows[4];
#pragma unroll
  for (int k = 0; k < 4; k++) {
    int iv = idxs[k];
    rows[k] = (iv > 0) ? (C1 + (size_t)(b * LL + iv - 1) * DPROJ + DSSM) : (const unsigned short*)0;
  }
  const float4* cw4 = (const float4*)convw;
#pragma unroll
  for (int it = 0; it < 3; ++it) {
    int unit = tid + it * 256;         // 0..575 (4-col groups)
    if (unit >= CONVD / 4) break;
    int c4 = unit * 4;
    ushort4 rv[4];
#pragma unroll
    for (int k = 0; k < 4; ++k)
      rv[k] = rows[k] ? *(const ushort4*)(rows[k] + c4) : make_ushort4(0, 0, 0, 0);
    float4 w0 = cw4[c4], w1 = cw4[c4 + 1], w2 = cw4[c4 + 2], w3 = cw4[c4 + 3];
    float4 cb = *(const float4*)(convb + c4);
    float a0 = cb.x + b2f(rv[0].x) * w0.x + b2f(rv[1].x) * w0.y + b2f(rv[2].x) * w0.z + b2f(rv[3].x) * w0.w;
    float a1 = cb.y + b2f(rv[0].y) * w1.x + b2f(rv[1].y) * w1.y + b2f(rv[2].y) * w1.z + b2f(rv[3].y) * w1.w;
    float a2 = cb.z + b2f(rv[0].z) * w2.x + b2f(rv[1].z) * w2.y + b2f(rv[2].z) * w2.z + b2f(rv[3].z) * w2.w;
    float a3 = cb.w + b2f(rv[0].w) * w3.x + b2f(rv[1].w) * w3.y + b2f(rv[2].w) * w3.z + b2f(rv[3].w) * w3.w;
    ushort4 o;
    o.x = f2b(a0 / (1.f + __expf(-a0)));
    o.y = f2b(a1 / (1.f + __expf(-a1)));
    o.z = f2b(a2 / (1.f + __expf(-a2)));
    o.w = f2b(a3 / (1.f + __expf(-a3)));
    if (c4 < DSSM)            *(ushort4*)(x16 + (size_t)bl * DSSM + c4) = o;
    else if (c4 < DSSM + DST) *(ushort4*)(Bg16 + (size_t)bl * DST + (c4 - DSSM)) = o;
    else                      *(ushort4*)(Cg16 + (size_t)bl * DST + (c4 - DSSM - DST)) = o;
  }
  if (tid < NH) {
    float raw = b2f(C1[(size_t)bl * DPROJ + DSSM + CONVD + tid]) + dtbias[tid];
    float dtv = (raw > 20.f) ? raw : log1pf(__expf(raw));
    dtb[(size_t)bl * NH + tid] = dtv;
  }
}

// ---------------- SSD intra-chunk: Yd, per-chunk states^T, decays ----------------
// 4 barriers; wave0 shfl-scan; states stored TRANSPOSED [p][n] (A=xT, B=BTw role swap)
__global__ __launch_bounds__(256) void d1_intra(
    const unsigned short* __restrict__ x16, const unsigned short* __restrict__ Bg16,
    const unsigned short* __restrict__ Cg16, const float* __restrict__ dtb,
    const float* __restrict__ A_log,
    unsigned short* __restrict__ y16, unsigned short* __restrict__ statesb,
    float* __restrict__ cdb, float* __restrict__ acumb)
{
  int gid = blockIdx.x;
  int h = gid & 31, ci = (gid >> 5) & 31, b = gid >> 10;
  int tid = threadIdx.x, wave = tid >> 6, lane = tid & 63, q = lane >> 4, lr = lane & 15;

  __shared__ __align__(16) unsigned short BnG[CS * 136];  // B[s][n]; reused as G[t][s] (stride 72)
  __shared__ __align__(16) unsigned short BTw[DST * 72];  // B^T[n][s] * dec[s] * dt[s]
  __shared__ __align__(16) unsigned short xT[HD * 72];    // x^T[p][s]  (no dt)
  __shared__ float dt_s[CS], ac_s[CS], dec_s[CS];

  const size_t blbase = (size_t)b * LL + ci * CS;
  const size_t chbase = (size_t)(b * NC + ci) * NH + h;
  float Ah = -__expf(A_log[h]);

  // wave0: dt load + shuffle inclusive scan (no barriers)
  if (wave == 0) {
    float d = dtb[(blbase + lane) * NH + h];
    float a = d * Ah;
#pragma unroll
    for (int off = 1; off < 64; off <<= 1) {
      float u = __shfl_up(a, off, 64);
      if (lane >= off) a += u;
    }
    float tot = __shfl(a, 63, 64);
    dt_s[lane] = d;
    ac_s[lane] = a;
    dec_s[lane] = __expf(tot - a);
    acumb[chbase * CS + lane] = a;
    if (lane == 0) cdb[chbase] = __expf(tot);
  }

  // stage B tile (64 x 128) and x^T (64p x 64s)
#pragma unroll
  for (int g = 0; g < 8; ++g) {
    int f = g * 256 + tid;              // s(64) x n-quads(32)
    int s = f >> 5, c4 = (f & 31) * 4;
    *(ushort4*)&BnG[s * 136 + c4] = *(const ushort4*)(Bg16 + (blbase + s) * DST + c4);
  }
#pragma unroll
  for (int g = 0; g < 4; ++g) {
    int f = g * 256 + tid;              // s(64) x p-quads(16)
    int s = f >> 4, p4 = (f & 15) * 4;
    ushort4 xv = *(const ushort4*)(x16 + (blbase + s) * DSSM + h * HD + p4);
    xT[(p4 + 0) * 72 + s] = xv.x;
    xT[(p4 + 1) * 72 + s] = xv.y;
    xT[(p4 + 2) * 72 + s] = xv.z;
    xT[(p4 + 3) * 72 + s] = xv.w;
  }
  __syncthreads();                      // barrier 1

  // BTw[n][s] = B[s][n] * dec[s] * dt[s]
#pragma unroll
  for (int g = 0; g < 4; ++g) {
    int f = g * 256 + tid;              // n(128) x sg(8)
    int n = f >> 3, sg = f & 7;
    int s0 = sg * 8;
    ushort4 lo, hi;
    lo.x = f2b(b2f(BnG[(s0 + 0) * 136 + n]) * dec_s[s0 + 0] * dt_s[s0 + 0]);
    lo.y = f2b(b2f(BnG[(s0 + 1) * 136 + n]) * dec_s[s0 + 1] * dt_s[s0 + 1]);
    lo.z = f2b(b2f(BnG[(s0 + 2) * 136 + n]) * dec_s[s0 + 2] * dt_s[s0 + 2]);
    lo.w = f2b(b2f(BnG[(s0 + 3) * 136 + n]) * dec_s[s0 + 3] * dt_s[s0 + 3]);
    hi.x = f2b(b2f(BnG[(s0 + 4) * 136 + n]) * dec_s[s0 + 4] * dt_s[s0 + 4]);
    hi.y = f2b(b2f(BnG[(s0 + 5) * 136 + n]) * dec_s[s0 + 5] * dt_s[s0 + 5]);
    hi.z = f2b(b2f(BnG[(s0 + 6) * 136 + n]) * dec_s[s0 + 6] * dt_s[s0 + 6]);
    hi.w = f2b(b2f(BnG[(s0 + 7) * 136 + n]) * dec_s[s0 + 7] * dt_s[s0 + 7]);
    *(ushort4*)&BTw[n * 72 + s0] = lo;
    *(ushort4*)&BTw[n * 72 + s0 + 4] = hi;
  }

  // S[t][s] = sum_n C[t][n] * B[s][n]  (C A-fragments direct from global)
  v4f accS[4];
#pragma unroll
  for (int i = 0; i < 4; i++) accS[i] = v4f{0.f, 0.f, 0.f, 0.f};
#pragma unroll
  for (int ks = 0; ks < 128; ks += 32) {
    v8s a = *(const v8s*)(Cg16 + (blbase + wave * 16 + lr) * DST + ks + q * 8);
#pragma unroll
    for (int si = 0; si < 4; ++si) {
      v8s bb = *(const v8s*)&BnG[(si * 16 + lr) * 136 + ks + q * 8];
      accS[si] = mfma16(a, bb, accS[si]);
    }
  }
  __syncthreads();                      // barrier 2 (BnG reads done)

  // G[t][s] = S * exp(Acum[t]-Acum[s]) * dt[s], masked s<=t; stride 72
  {
    int tbase = wave * 16 + q * 4;
#pragma unroll
    for (int si = 0; si < 4; ++si) {
      int s = si * 16 + lr;
      float ds = dt_s[s], as = ac_s[s];
#pragma unroll
      for (int r = 0; r < 4; ++r) {
        int tt = tbase + r;
        float g = 0.f;
        if (s <= tt) g = accS[si][r] * __expf(ac_s[tt] - as) * ds;
        BnG[tt * 72 + s] = f2b(g);
      }
    }
  }
  __syncthreads();                      // barrier 3

  // Yd[t][p] = G @ x ; states^T[p][n] = sum_s xT[p][s]*BTw[n][s]
  v4f accY[4], accPT[4][2];
#pragma unroll
  for (int i = 0; i < 4; i++) {
    accY[i] = v4f{0.f,0.f,0.f,0.f};
    accPT[i][0] = v4f{0.f,0.f,0.f,0.f};
    accPT[i][1] = v4f{0.f,0.f,0.f,0.f};
  }
  int nw = wave * 32;                   // wave covers n in [nw, nw+32)
#pragma unroll
  for (int ks = 0; ks < 64; ks += 32) {
    v8s xf[4];
#pragma unroll
    for (int i = 0; i < 4; ++i) xf[i] = *(const v8s*)&xT[(i * 16 + lr) * 72 + ks + q * 8];
    v8s aG  = *(const v8s*)&BnG[(wave * 16 + lr) * 72 + ks + q * 8];
    v8s bw0 = *(const v8s*)&BTw[(nw + lr) * 72 + ks + q * 8];
    v8s bw1 = *(const v8s*)&BTw[(nw + 16 + lr) * 72 + ks + q * 8];
#pragma unroll
    for (int nt = 0; nt < 4; ++nt) {
      accY[nt] = mfma16(aG, xf[nt], accY[nt]);
      accPT[nt][0] = mfma16(xf[nt], bw0, accPT[nt][0]);
      accPT[nt][1] = mfma16(xf[nt], bw1, accPT[nt][1]);
    }
  }

  // epilogue: Yd
#pragma unroll
  for (int nt = 0; nt < 4; ++nt) {
    int p = nt * 16 + lr;
#pragma unroll
    for (int r = 0; r < 4; ++r) {
      int t = wave * 16 + q * 4 + r;
      y16[(blbase + t) * DSSM + h * HD + p] = f2b(accY[nt][r]);
    }
  }
  // epilogue: states^T  (layout [p][n], p<HD rows, n<DST cols)
  size_t sbase = chbase * (DST * HD);
#pragma unroll
  for (int mt = 0; mt < 4; ++mt) {
#pragma unroll
    for (int nt = 0; nt < 2; ++nt) {
      int n = nw + nt * 16 + lr;
#pragma unroll
      for (int r = 0; r < 4; ++r) {
        int p = mt * 16 + q * 4 + r;
        statesb[sbase + (size_t)p * DST + n] = f2b(accPT[mt][nt][r]);
      }
    }
  }
}

// ---------------- state passing: all loads upfront, register scan ----------------
// 2048 blocks: (b,h) x 32 segments of the 8192-elem state; 1 elem/thread over 32 chunks
__global__ __launch_bounds__(256) void d2_scan(
    unsigned short* __restrict__ statesb, const float* __restrict__ cdb)
{
  int g = blockIdx.x;
  int seg = g & 31, bh = g >> 5;
  int b = bh >> 5, h = bh & 31;
  int e = seg * 256 + threadIdx.x;      // 0..8191
  const size_t cstride = (size_t)NH * DST * HD;
  size_t base = ((size_t)(b * NC) * NH + h) * (DST * HD) + e;
  unsigned short st[NC];
#pragma unroll
  for (int ci = 0; ci < NC; ++ci) st[ci] = statesb[base + ci * cstride];
  float run = 0.f;
#pragma unroll
  for (int ci = 0; ci < NC; ++ci) {
    float cd = cdb[(b * NC + ci) * NH + h];
    statesb[base + ci * cstride] = f2b(run);   // prev entering chunk ci
    run = run * cd + b2f(st[ci]);
  }
}

// ---------------- SSD inter-chunk: Y += exp(Acum[t]) * C @ prev^T + D*x ----------------
// prev stored [p][n] -> straight vector staging, no transpose
__global__ __launch_bounds__(256) void d3_inter(
    const unsigned short* __restrict__ x16, const unsigned short* __restrict__ Cg16,
    const unsigned short* __restrict__ statesb, const float* __restrict__ acumb,
    const float* __restrict__ Dp, unsigned short* __restrict__ y16)
{
  int gid = blockIdx.x;
  int h = gid & 31, ci = (gid >> 5) & 31, b = gid >> 10;
  int tid = threadIdx.x, wave = tid >> 6, lane = tid & 63, q = lane >> 4, lr = lane & 15;
  __shared__ __align__(16) unsigned short pT[HD * 136];   // prev^T[p][n]
  __shared__ __align__(16) float ys[CS * 68];             // y-stage (fp32)
  __shared__ float ea[CS];
  const size_t blbase = (size_t)b * LL + ci * CS;
  const size_t chbase = (size_t)(b * NC + ci) * NH + h;
  if (tid < CS) ea[tid] = __expf(acumb[chbase * CS + tid]);
  size_t sbase = chbase * (DST * HD);
  // stage prev^T: plain vector copy (64 rows x 128 cols)
#pragma unroll
  for (int g = 0; g < 8; ++g) {
    int f = g * 256 + tid;              // p(64) x n-quads(32)
    int p = f >> 5, c4 = (f & 31) * 4;
    *(ushort4*)&pT[p * 136 + c4] = *(const ushort4*)(statesb + sbase + (size_t)p * DST + c4);
  }
  __syncthreads();
  v4f acc[4];
#pragma unroll
  for (int i = 0; i < 4; i++) acc[i] = v4f{0.f, 0.f, 0.f, 0.f};
#pragma unroll
  for (int ks = 0; ks < 128; ks += 32) {
    v8s a = *(const v8s*)(Cg16 + (blbase + wave * 16 + lr) * DST + ks + q * 8);
#pragma unroll
    for (int nt = 0; nt < 4; ++nt) {
      v8s bb = *(const v8s*)&pT[(nt * 16 + lr) * 136 + ks + q * 8];
      acc[nt] = mfma16(a, bb, acc[nt]);
    }
  }
  // stage Yoff to LDS (fp32), then vectorized RMW epilogue
#pragma unroll
  for (int nt = 0; nt < 4; ++nt) {
#pragma unroll
    for (int r = 0; r < 4; ++r)
      ys[(wave * 16 + q * 4 + r) * 68 + nt * 16 + lr] = acc[nt][r];
  }
  __syncthreads();
  float Dh = Dp[h];
#pragma unroll
  for (int it = 0; it < 2; ++it) {
    int unit = it * 256 + tid;          // t(64) x p8(8)
    int t = unit >> 3, p8 = (unit & 7) * 8;
    float ea_t = ea[t];
    size_t off = (blbase + t) * DSSM + h * HD + p8;
    uint4 yv = *(const uint4*)(y16 + off);
    uint4 xv = *(const uint4*)(x16 + off);
    float4 o0 = *(const float4*)&ys[t * 68 + p8];
    float4 o1 = *(const float4*)&ys[t * 68 + p8 + 4];
    const unsigned int* yu = (const unsigned int*)&yv;
    const unsigned int* xu = (const unsigned int*)&xv;
    float oo[8] = {o0.x, o0.y, o0.z, o0.w, o1.x, o1.y, o1.z, o1.w};
    unsigned int ro[4];
#pragma unroll
    for (int d = 0; d < 4; ++d) {
      unsigned short y0 = (unsigned short)(yu[d] & 0xffffu), y1 = (unsigned short)(yu[d] >> 16);
      unsigned short x0 = (unsigned short)(xu[d] & 0xffffu), x1 = (unsigned short)(xu[d] >> 16);
      float v0 = b2f(y0) + ea_t * oo[d * 2 + 0] + Dh * b2f(x0);
      float v1 = b2f(y1) + ea_t * oo[d * 2 + 1] + Dh * b2f(x1);
      ro[d] = (unsigned int)f2b(v0) | ((unsigned int)f2b(v1) << 16);
    }
    *(uint4*)(y16 + off) = make_uint4(ro[0], ro[1], ro[2], ro[3]);
  }
}

// ---------------- gated RMSNorm (vectorized) ----------------
__global__ __launch_bounds__(256) void norm_kernel(
    const unsigned short* __restrict__ y16, const unsigned short* __restrict__ C1,
    const float* __restrict__ normw, unsigned short* __restrict__ yzn)
{
  int bl = blockIdx.x;
  int tid = threadIdx.x;
  int wave = tid >> 6, lane = tid & 63;
  int c8 = tid * 8;
  uint4 yv = *(const uint4*)(y16 + (size_t)bl * DSSM + c8);
  uint4 zv = *(const uint4*)(C1 + (size_t)bl * DPROJ + c8);   // z = first 2048 cols
  const unsigned int* yu = (const unsigned int*)&yv;
  const unsigned int* zu = (const unsigned int*)&zv;
  float vals[8];
  float ss = 0.f;
#pragma unroll
  for (int d = 0; d < 4; ++d) {
    unsigned short y0 = (unsigned short)(yu[d] & 0xffffu), y1 = (unsigned short)(yu[d] >> 16);
    unsigned short z0 = (unsigned short)(zu[d] & 0xffffu), z1 = (unsigned short)(zu[d] >> 16);
    float zf0 = b2f(z0), zf1 = b2f(z1);
    float v0 = b2f(y0) * (zf0 / (1.f + __expf(-zf0)));
    float v1 = b2f(y1) * (zf1 / (1.f + __expf(-zf1)));
    vals[d * 2] = v0; vals[d * 2 + 1] = v1;
    ss += v0 * v0 + v1 * v1;
  }
#pragma unroll
  for (int off = 32; off > 0; off >>= 1) ss += __shfl_down(ss, off);
  __shared__ float red[4];
  if (lane == 0) red[wave] = ss;
  __syncthreads();
  float tot = red[0] + red[1] + red[2] + red[3];
  float scale = rsqrtf(tot * (1.f / 2048.f) + 1e-5f);
  float4 w0 = *(const float4*)(normw + c8);
  float4 w1 = *(const float4*)(normw + c8 + 4);
  float ws[8] = {w0.x, w0.y, w0.z, w0.w, w1.x, w1.y, w1.z, w1.w};
  unsigned int ro[4];
#pragma unroll
  for (int d = 0; d < 4; ++d) {
    unsigned short r0 = f2b(vals[d * 2] * scale * ws[d * 2]);
    unsigned short r1 = f2b(vals[d * 2 + 1] * scale * ws[d * 2 + 1]);
    ro[d] = (unsigned int)r0 | ((unsigned int)r1 << 16);
  }
  *(uint4*)(yzn + (size_t)bl * DSSM + c8) = make_uint4(ro[0], ro[1], ro[2], ro[3]);
}

// ---------------- host launch ----------------
extern "C" void kernel_launch(void* const* d_in, const int* in_sizes, int n_in,
                              void* d_out, int out_size, void* d_ws, size_t ws_size,
                              hipStream_t stream) {
  const float* u      = (const float*)d_in[0];
  const int*   cidx   = (const int*)d_in[1];
  const float* W_in   = (const float*)d_in[2];
  const float* convw  = (const float*)d_in[3];
  const float* convb  = (const float*)d_in[4];
  const float* dtbias = (const float*)d_in[5];
  const float* A_log  = (const float*)d_in[6];
  const float* Dp     = (const float*)d_in[7];
  const float* normw  = (const float*)d_in[8];
  const float* W_out  = (const float*)d_in[9];

  char* w = (char*)d_ws;
  size_t off = 0;
  auto alloc = [&](size_t bytes) { char* p = w + off; off += (bytes + 255) & ~(size_t)255; return p; };
  unsigned short* u16     = (unsigned short*)alloc((size_t)BLTOT * DMODEL * 2);
  unsigned short* Win16   = (unsigned short*)alloc((size_t)DPROJ * DMODEL * 2);
  unsigned short* Wout16  = (unsigned short*)alloc((size_t)DMODEL * DSSM * 2);
  unsigned short* C1      = (unsigned short*)alloc((size_t)BLTOT * DPROJ * 2);
  unsigned short* x16     = (unsigned short*)alloc((size_t)BLTOT * DSSM * 2);
  unsigned short* Bg16    = (unsigned short*)alloc((size_t)BLTOT * DST * 2);
  unsigned short* Cg16    = (unsigned short*)alloc((size_t)BLTOT * DST * 2);
  float*          dtb     = (float*)alloc((size_t)BLTOT * NH * 4);
  float*          acumb   = (float*)alloc((size_t)BB * NC * NH * CS * 4);
  unsigned short* y16     = (unsigned short*)alloc((size_t)BLTOT * DSSM * 2);
  unsigned short* statesb = (unsigned short*)alloc((size_t)BB * NC * NH * DST * HD * 2);
  float*          cdb     = (float*)alloc((size_t)BB * NC * NH * 4);
  unsigned short* yzn     = (unsigned short*)alloc((size_t)BLTOT * DSSM * 2);

  const int na4 = BLTOT * DMODEL / 4, nb4 = DPROJ * DMODEL / 4, nc4 = DMODEL * DSSM / 4;
  cvt3_kernel<<<(na4 + nb4 + nc4 + 255) / 256, 256, 0, stream>>>(
      u, u16, na4, W_in, Win16, nb4, W_out, Wout16, nc4);

  // zxbcdt = u @ W_in^T   (bf16 out, ld 4384) — 256x128 tiles, 512 threads
  gemm_big<<<dim3(BLTOT / 256, (DPROJ + 127) / 128), 512, 0, stream>>>(
      u16, Win16, C1, BLTOT, DPROJ, DMODEL, DPROJ);
  conv_kernel<<<BLTOT, 256, 0, stream>>>(C1, cidx, convw, convb, dtbias, x16, Bg16, Cg16, dtb);
  d1_intra<<<BB * NC * NH, 256, 0, stream>>>(x16, Bg16, Cg16, dtb, A_log, y16, statesb, cdb, acumb);
  d2_scan<<<BB * NH * 32, 256, 0, stream>>>(statesb, cdb);
  d3_inter<<<BB * NC * NH, 256, 0, stream>>>(x16, Cg16, statesb, acumb, Dp, y16);
  norm_kernel<<<BLTOT, 256, 0, stream>>>(y16, C1, normw, yzn);
  // out = yzn @ W_out^T   (fp32 out) — 128x64 tiles for 512 blocks (2+/CU)
  gemm_bt<64, 0><<<dim3(BLTOT / 128, DMODEL / 64), 256, 0, stream>>>(
      yzn, Wout16, (float*)d_out, BLTOT, DMODEL, DSSM, DMODEL);
}

// Round 7
// 260.837 us; speedup vs baseline: 1.1613x; 1.0403x over previous
//
#include <hip/hip_runtime.h>

// ---- problem constants ----
#define BB 2
#define LL 2048
#define DMODEL 1024
#define DSSM 2048
#define NH 32
#define HD 64
#define DST 128
#define CONVD 2304
#define DPROJ 4384
#define CS 64               // SSD chunk size (rechunked; math is exact)
#define NC 32               // LL/CS
#define BLTOT (BB*LL)       // 4096

typedef short v8s __attribute__((ext_vector_type(8)));
typedef float v4f __attribute__((ext_vector_type(4)));

__device__ __forceinline__ float b2f(unsigned short h) {
  union { unsigned int u; float f; } v; v.u = ((unsigned int)h) << 16; return v.f;
}
__device__ __forceinline__ unsigned short f2b(float f) {
  union { float f; unsigned int u; } v; v.f = f;
  unsigned int u = v.u;
  return (unsigned short)((u + 0x7fffu + ((u >> 16) & 1u)) >> 16);
}
__device__ __forceinline__ v4f mfma16(v8s a, v8s b, v4f c) {
  return __builtin_amdgcn_mfma_f32_16x16x32_bf16(a, b, c, 0, 0, 0);
}
// async global->LDS, 16B per lane; LDS dest = wave-uniform base + lane*16
__device__ __forceinline__ void gl_lds16(const unsigned short* g, unsigned short* l) {
  __builtin_amdgcn_global_load_lds(
      (const __attribute__((address_space(1))) void*)(g),
      (__attribute__((address_space(3))) void*)(l), 16, 0, 0);
}

// ---------------- fused fp32 -> bf16 conversion (3 tensors, 1 launch) ----------------
__global__ __launch_bounds__(256) void cvt3_kernel(
    const float* __restrict__ a, unsigned short* __restrict__ oa, int na4,
    const float* __restrict__ b, unsigned short* __restrict__ ob, int nb4,
    const float* __restrict__ c, unsigned short* __restrict__ oc, int nc4)
{
  int i = blockIdx.x * 256 + threadIdx.x;
  const float* src; unsigned short* dst; int j;
  if (i < na4) { src = a; dst = oa; j = i; }
  else if (i < na4 + nb4) { src = b; dst = ob; j = i - na4; }
  else if (i < na4 + nb4 + nc4) { src = c; dst = oc; j = i - na4 - nb4; }
  else return;
  float4 v = ((const float4*)src)[j];
  ushort4 o;
  o.x = f2b(v.x); o.y = f2b(v.y); o.z = f2b(v.z); o.w = f2b(v.w);
  ((ushort4*)dst)[j] = o;
}

// ---------------- bf16 GEMM: 128 x TN tile, 256 threads ----------------
// m97 structure: global_load_lds width=16 staging, unpadded LDS, XOR chunk swizzle.
template<int TN, int OUT_BF16>
__global__ __launch_bounds__(256) void gemm_bt(
    const unsigned short* __restrict__ A, const unsigned short* __restrict__ Bt,
    void* __restrict__ Cout, int M, int N, int K, int ldc)
{
  constexpr int NT = TN / 32;                 // n-tiles per wave
  const int bm = blockIdx.x, bn = blockIdx.y;
  const int tid = threadIdx.x;
  const int wave = tid >> 6, lane = tid & 63;
  const int wm = wave & 1, wn = wave >> 1;
  const int q = lane >> 4, lr = lane & 15;

  __shared__ __align__(16) unsigned short As[128 * 64];
  __shared__ __align__(16) unsigned short Bs[TN * 64];

  v4f acc[4][NT];
#pragma unroll
  for (int i = 0; i < 4; i++)
#pragma unroll
    for (int j = 0; j < NT; j++) acc[i][j] = v4f{0.f, 0.f, 0.f, 0.f};

  const int lrow = lane >> 3;                 // 0..7 (row within 8-row group)
  const int gchunk = (lane & 7) ^ lrow;       // swizzled source 16B-chunk

  for (int k0 = 0; k0 < K; k0 += 64) {
    __syncthreads();
#pragma unroll
    for (int it = 0; it < 4; ++it) {
      int r = wave * 32 + it * 8 + lrow;
      gl_lds16(A + (size_t)(bm * 128 + r) * K + k0 + gchunk * 8,
               &As[(wave * 32 + it * 8) * 64]);
    }
#pragma unroll
    for (int it = 0; it < TN / 32; ++it) {
      int rloc = wave * (TN / 4) + it * 8;
      int rb = bn * TN + rloc + lrow; if (rb >= N) rb = N - 1;  // clamp; junk never stored
      gl_lds16(Bt + (size_t)rb * K + k0 + gchunk * 8, &Bs[rloc * 64]);
    }
    __syncthreads();
#pragma unroll
    for (int ks = 0; ks < 64; ks += 32) {
      const int c0 = (ks >> 3) + q;           // 16B-chunk index 0..7
      v8s af[4], bf[NT];
#pragma unroll
      for (int mt = 0; mt < 4; ++mt) {
        int r = wm * 64 + mt * 16 + lr;
        af[mt] = *(const v8s*)&As[r * 64 + ((c0 ^ (r & 7)) << 3)];
      }
#pragma unroll
      for (int nt = 0; nt < NT; ++nt) {
        int r = wn * (TN / 2) + nt * 16 + lr;
        bf[nt] = *(const v8s*)&Bs[r * 64 + ((c0 ^ (r & 7)) << 3)];
      }
#pragma unroll
      for (int mt = 0; mt < 4; ++mt)
#pragma unroll
        for (int nt = 0; nt < NT; ++nt)
          acc[mt][nt] = mfma16(af[mt], bf[nt], acc[mt][nt]);
    }
  }
#pragma unroll
  for (int mt = 0; mt < 4; ++mt) {
#pragma unroll
    for (int nt = 0; nt < NT; ++nt) {
      int row = bm * 128 + wm * 64 + mt * 16 + q * 4;
      int col = bn * TN + wn * (TN / 2) + nt * 16 + lr;
      if (col < N) {
#pragma unroll
        for (int r = 0; r < 4; ++r) {
          float v = acc[mt][nt][r];
          if (OUT_BF16) ((unsigned short*)Cout)[(size_t)(row + r) * ldc + col] = f2b(v);
          else          ((float*)Cout)[(size_t)(row + r) * ldc + col] = v;
        }
      }
    }
  }
}

// ---------------- tree conv + SiLU + dt softplus: 4 tokens/block ----------------
// Weights held in registers across the 4-token loop (was: reloaded per token).
__global__ __launch_bounds__(256) void conv_kernel(
    const unsigned short* __restrict__ C1, const int* __restrict__ cidx,
    const float* __restrict__ convw, const float* __restrict__ convb,
    const float* __restrict__ dtbias,
    unsigned short* __restrict__ x16, unsigned short* __restrict__ Bg16,
    unsigned short* __restrict__ Cg16, float* __restrict__ dtb)
{
  int bl0 = blockIdx.x * 4;            // 4 consecutive tokens (never cross batch: 2048%4==0)
  int b = bl0 >> 11;
  int tid = threadIdx.x;
  __shared__ int idxs[16];
  if (tid < 16) {
    int tk = tid >> 2, k = tid & 3;
    idxs[tid] = cidx[b * (4 * LL) + (((bl0 + tk) & 2047) * 4) + k];
  }
  __syncthreads();
  const float4* cw4 = (const float4*)convw;
#pragma unroll
  for (int it = 0; it < 3; ++it) {
    int unit = tid + it * 256;         // 0..575 (4-col groups)
    if (unit >= CONVD / 4) break;
    int c4 = unit * 4;
    float4 w0 = cw4[c4], w1 = cw4[c4 + 1], w2 = cw4[c4 + 2], w3 = cw4[c4 + 3];
    float4 cb = *(const float4*)(convb + c4);
#pragma unroll
    for (int tk = 0; tk < 4; ++tk) {
      int bl = bl0 + tk;
      ushort4 rv[4];
#pragma unroll
      for (int k = 0; k < 4; ++k) {
        int iv = idxs[tk * 4 + k];
        rv[k] = (iv > 0) ? *(const ushort4*)(C1 + (size_t)(b * LL + iv - 1) * DPROJ + DSSM + c4)
                         : make_ushort4(0, 0, 0, 0);
      }
      float a0 = cb.x + b2f(rv[0].x) * w0.x + b2f(rv[1].x) * w0.y + b2f(rv[2].x) * w0.z + b2f(rv[3].x) * w0.w;
      float a1 = cb.y + b2f(rv[0].y) * w1.x + b2f(rv[1].y) * w1.y + b2f(rv[2].y) * w1.z + b2f(rv[3].y) * w1.w;
      float a2 = cb.z + b2f(rv[0].z) * w2.x + b2f(rv[1].z) * w2.y + b2f(rv[2].z) * w2.z + b2f(rv[3].z) * w2.w;
      float a3 = cb.w + b2f(rv[0].w) * w3.x + b2f(rv[1].w) * w3.y + b2f(rv[2].w) * w3.z + b2f(rv[3].w) * w3.w;
      ushort4 o;
      o.x = f2b(a0 / (1.f + __expf(-a0)));
      o.y = f2b(a1 / (1.f + __expf(-a1)));
      o.z = f2b(a2 / (1.f + __expf(-a2)));
      o.w = f2b(a3 / (1.f + __expf(-a3)));
      if (c4 < DSSM)            *(ushort4*)(x16 + (size_t)bl * DSSM + c4) = o;
      else if (c4 < DSSM + DST) *(ushort4*)(Bg16 + (size_t)bl * DST + (c4 - DSSM)) = o;
      else                      *(ushort4*)(Cg16 + (size_t)bl * DST + (c4 - DSSM - DST)) = o;
    }
  }
  if (tid < 4 * NH) {                  // 4 tokens x 32 heads
    int tk = tid >> 5, hh = tid & 31;
    int bl = bl0 + tk;
    float raw = b2f(C1[(size_t)bl * DPROJ + DSSM + CONVD + hh]) + dtbias[hh];
    float dtv = (raw > 20.f) ? raw : log1pf(__expf(raw));
    dtb[(size_t)bl * NH + hh] = dtv;
  }
}

// ---------------- SSD intra-chunk: Yd + D*x, per-chunk states^T, decays ----------------
// 4 barriers; wave0 shfl-scan; states stored TRANSPOSED [p][n]; D*x folded into y-epilogue
__global__ __launch_bounds__(256) void d1_intra(
    const unsigned short* __restrict__ x16, const unsigned short* __restrict__ Bg16,
    const unsigned short* __restrict__ Cg16, const float* __restrict__ dtb,
    const float* __restrict__ A_log, const float* __restrict__ Dp,
    unsigned short* __restrict__ y16, unsigned short* __restrict__ statesb,
    float* __restrict__ cdb, float* __restrict__ acumb)
{
  int gid = blockIdx.x;
  int h = gid & 31, ci = (gid >> 5) & 31, b = gid >> 10;
  int tid = threadIdx.x, wave = tid >> 6, lane = tid & 63, q = lane >> 4, lr = lane & 15;

  __shared__ __align__(16) unsigned short BnG[CS * 136];  // B[s][n]; reused as G[t][s] (stride 72)
  __shared__ __align__(16) unsigned short BTw[DST * 72];  // B^T[n][s] * dec[s] * dt[s]
  __shared__ __align__(16) unsigned short xT[HD * 72];    // x^T[p][s]  (no dt)
  __shared__ float dt_s[CS], ac_s[CS], dec_s[CS];

  const size_t blbase = (size_t)b * LL + ci * CS;
  const size_t chbase = (size_t)(b * NC + ci) * NH + h;
  float Ah = -__expf(A_log[h]);

  // wave0: dt load + shuffle inclusive scan (no barriers)
  if (wave == 0) {
    float d = dtb[(blbase + lane) * NH + h];
    float a = d * Ah;
#pragma unroll
    for (int off = 1; off < 64; off <<= 1) {
      float u = __shfl_up(a, off, 64);
      if (lane >= off) a += u;
    }
    float tot = __shfl(a, 63, 64);
    dt_s[lane] = d;
    ac_s[lane] = a;
    dec_s[lane] = __expf(tot - a);
    acumb[chbase * CS + lane] = a;
    if (lane == 0) cdb[chbase] = __expf(tot);
  }

  // stage B tile (64 x 128) and x^T (64p x 64s)
#pragma unroll
  for (int g = 0; g < 8; ++g) {
    int f = g * 256 + tid;              // s(64) x n-quads(32)
    int s = f >> 5, c4 = (f & 31) * 4;
    *(ushort4*)&BnG[s * 136 + c4] = *(const ushort4*)(Bg16 + (blbase + s) * DST + c4);
  }
#pragma unroll
  for (int g = 0; g < 4; ++g) {
    int f = g * 256 + tid;              // s(64) x p-quads(16)
    int s = f >> 4, p4 = (f & 15) * 4;
    ushort4 xv = *(const ushort4*)(x16 + (blbase + s) * DSSM + h * HD + p4);
    xT[(p4 + 0) * 72 + s] = xv.x;
    xT[(p4 + 1) * 72 + s] = xv.y;
    xT[(p4 + 2) * 72 + s] = xv.z;
    xT[(p4 + 3) * 72 + s] = xv.w;
  }
  __syncthreads();                      // barrier 1

  // BTw[n][s] = B[s][n] * dec[s] * dt[s]
#pragma unroll
  for (int g = 0; g < 4; ++g) {
    int f = g * 256 + tid;              // n(128) x sg(8)
    int n = f >> 3, sg = f & 7;
    int s0 = sg * 8;
    ushort4 lo, hi;
    lo.x = f2b(b2f(BnG[(s0 + 0) * 136 + n]) * dec_s[s0 + 0] * dt_s[s0 + 0]);
    lo.y = f2b(b2f(BnG[(s0 + 1) * 136 + n]) * dec_s[s0 + 1] * dt_s[s0 + 1]);
    lo.z = f2b(b2f(BnG[(s0 + 2) * 136 + n]) * dec_s[s0 + 2] * dt_s[s0 + 2]);
    lo.w = f2b(b2f(BnG[(s0 + 3) * 136 + n]) * dec_s[s0 + 3] * dt_s[s0 + 3]);
    hi.x = f2b(b2f(BnG[(s0 + 4) * 136 + n]) * dec_s[s0 + 4] * dt_s[s0 + 4]);
    hi.y = f2b(b2f(BnG[(s0 + 5) * 136 + n]) * dec_s[s0 + 5] * dt_s[s0 + 5]);
    hi.z = f2b(b2f(BnG[(s0 + 6) * 136 + n]) * dec_s[s0 + 6] * dt_s[s0 + 6]);
    hi.w = f2b(b2f(BnG[(s0 + 7) * 136 + n]) * dec_s[s0 + 7] * dt_s[s0 + 7]);
    *(ushort4*)&BTw[n * 72 + s0] = lo;
    *(ushort4*)&BTw[n * 72 + s0 + 4] = hi;
  }

  // S[t][s] = sum_n C[t][n] * B[s][n]  (C A-fragments direct from global)
  v4f accS[4];
#pragma unroll
  for (int i = 0; i < 4; i++) accS[i] = v4f{0.f, 0.f, 0.f, 0.f};
#pragma unroll
  for (int ks = 0; ks < 128; ks += 32) {
    v8s a = *(const v8s*)(Cg16 + (blbase + wave * 16 + lr) * DST + ks + q * 8);
#pragma unroll
    for (int si = 0; si < 4; ++si) {
      v8s bb = *(const v8s*)&BnG[(si * 16 + lr) * 136 + ks + q * 8];
      accS[si] = mfma16(a, bb, accS[si]);
    }
  }
  __syncthreads();                      // barrier 2 (BnG reads done)

  // G[t][s] = S * exp(Acum[t]-Acum[s]) * dt[s], masked s<=t; stride 72
  {
    int tbase = wave * 16 + q * 4;
#pragma unroll
    for (int si = 0; si < 4; ++si) {
      int s = si * 16 + lr;
      float ds = dt_s[s], as = ac_s[s];
#pragma unroll
      for (int r = 0; r < 4; ++r) {
        int tt = tbase + r;
        float g = 0.f;
        if (s <= tt) g = accS[si][r] * __expf(ac_s[tt] - as) * ds;
        BnG[tt * 72 + s] = f2b(g);
      }
    }
  }
  __syncthreads();                      // barrier 3

  // Yd[t][p] = G @ x ; states^T[p][n] = sum_s xT[p][s]*BTw[n][s]
  v4f accY[4], accPT[4][2];
#pragma unroll
  for (int i = 0; i < 4; i++) {
    accY[i] = v4f{0.f,0.f,0.f,0.f};
    accPT[i][0] = v4f{0.f,0.f,0.f,0.f};
    accPT[i][1] = v4f{0.f,0.f,0.f,0.f};
  }
  int nw = wave * 32;                   // wave covers n in [nw, nw+32)
#pragma unroll
  for (int ks = 0; ks < 64; ks += 32) {
    v8s xf[4];
#pragma unroll
    for (int i = 0; i < 4; ++i) xf[i] = *(const v8s*)&xT[(i * 16 + lr) * 72 + ks + q * 8];
    v8s aG  = *(const v8s*)&BnG[(wave * 16 + lr) * 72 + ks + q * 8];
    v8s bw0 = *(const v8s*)&BTw[(nw + lr) * 72 + ks + q * 8];
    v8s bw1 = *(const v8s*)&BTw[(nw + 16 + lr) * 72 + ks + q * 8];
#pragma unroll
    for (int nt = 0; nt < 4; ++nt) {
      accY[nt] = mfma16(aG, xf[nt], accY[nt]);
      accPT[nt][0] = mfma16(xf[nt], bw0, accPT[nt][0]);
      accPT[nt][1] = mfma16(xf[nt], bw1, accPT[nt][1]);
    }
  }

  // epilogue: y = Yd + D*x  (x from LDS xT)
  float Dh = Dp[h];
#pragma unroll
  for (int nt = 0; nt < 4; ++nt) {
    int p = nt * 16 + lr;
#pragma unroll
    for (int r = 0; r < 4; ++r) {
      int t = wave * 16 + q * 4 + r;
      float xv = b2f(xT[p * 72 + t]);
      y16[(blbase + t) * DSSM + h * HD + p] = f2b(accY[nt][r] + Dh * xv);
    }
  }
  // epilogue: states^T  (layout [p][n], p<HD rows, n<DST cols)
  size_t sbase = chbase * (DST * HD);
#pragma unroll
  for (int mt = 0; mt < 4; ++mt) {
#pragma unroll
    for (int nt = 0; nt < 2; ++nt) {
      int n = nw + nt * 16 + lr;
#pragma unroll
      for (int r = 0; r < 4; ++r) {
        int p = mt * 16 + q * 4 + r;
        statesb[sbase + (size_t)p * DST + n] = f2b(accPT[mt][nt][r]);
      }
    }
  }
}

// ---------------- state passing: all loads upfront, register scan ----------------
// 2048 blocks: (b,h) x 32 segments of the 8192-elem state; 1 elem/thread over 32 chunks
__global__ __launch_bounds__(256) void d2_scan(
    unsigned short* __restrict__ statesb, const float* __restrict__ cdb)
{
  int g = blockIdx.x;
  int seg = g & 31, bh = g >> 5;
  int b = bh >> 5, h = bh & 31;
  int e = seg * 256 + threadIdx.x;      // 0..8191
  const size_t cstride = (size_t)NH * DST * HD;
  size_t base = ((size_t)(b * NC) * NH + h) * (DST * HD) + e;
  unsigned short st[NC];
#pragma unroll
  for (int ci = 0; ci < NC; ++ci) st[ci] = statesb[base + ci * cstride];
  float run = 0.f;
#pragma unroll
  for (int ci = 0; ci < NC; ++ci) {
    float cd = cdb[(b * NC + ci) * NH + h];
    statesb[base + ci * cstride] = f2b(run);   // prev entering chunk ci
    run = run * cd + b2f(st[ci]);
  }
}

// ---------------- SSD inter-chunk: Y += exp(Acum[t]) * C @ prev^T ----------------
// prev stored [p][n] -> straight vector staging; D*x already folded into d1
__global__ __launch_bounds__(256) void d3_inter(
    const unsigned short* __restrict__ Cg16,
    const unsigned short* __restrict__ statesb, const float* __restrict__ acumb,
    unsigned short* __restrict__ y16)
{
  int gid = blockIdx.x;
  int h = gid & 31, ci = (gid >> 5) & 31, b = gid >> 10;
  int tid = threadIdx.x, wave = tid >> 6, lane = tid & 63, q = lane >> 4, lr = lane & 15;
  __shared__ __align__(16) unsigned short pT[HD * 136];   // prev^T[p][n]
  __shared__ __align__(16) float ys[CS * 68];             // y-stage (fp32)
  __shared__ float ea[CS];
  const size_t blbase = (size_t)b * LL + ci * CS;
  const size_t chbase = (size_t)(b * NC + ci) * NH + h;
  if (tid < CS) ea[tid] = __expf(acumb[chbase * CS + tid]);
  size_t sbase = chbase * (DST * HD);
  // stage prev^T: plain vector copy (64 rows x 128 cols)
#pragma unroll
  for (int g = 0; g < 8; ++g) {
    int f = g * 256 + tid;              // p(64) x n-quads(32)
    int p = f >> 5, c4 = (f & 31) * 4;
    *(ushort4*)&pT[p * 136 + c4] = *(const ushort4*)(statesb + sbase + (size_t)p * DST + c4);
  }
  __syncthreads();
  v4f acc[4];
#pragma unroll
  for (int i = 0; i < 4; i++) acc[i] = v4f{0.f, 0.f, 0.f, 0.f};
#pragma unroll
  for (int ks = 0; ks < 128; ks += 32) {
    v8s a = *(const v8s*)(Cg16 + (blbase + wave * 16 + lr) * DST + ks + q * 8);
#pragma unroll
    for (int nt = 0; nt < 4; ++nt) {
      v8s bb = *(const v8s*)&pT[(nt * 16 + lr) * 136 + ks + q * 8];
      acc[nt] = mfma16(a, bb, acc[nt]);
    }
  }
  // stage Yoff to LDS (fp32), then vectorized RMW epilogue
#pragma unroll
  for (int nt = 0; nt < 4; ++nt) {
#pragma unroll
    for (int r = 0; r < 4; ++r)
      ys[(wave * 16 + q * 4 + r) * 68 + nt * 16 + lr] = acc[nt][r];
  }
  __syncthreads();
#pragma unroll
  for (int it = 0; it < 2; ++it) {
    int unit = it * 256 + tid;          // t(64) x p8(8)
    int t = unit >> 3, p8 = (unit & 7) * 8;
    float ea_t = ea[t];
    size_t off = (blbase + t) * DSSM + h * HD + p8;
    uint4 yv = *(const uint4*)(y16 + off);
    float4 o0 = *(const float4*)&ys[t * 68 + p8];
    float4 o1 = *(const float4*)&ys[t * 68 + p8 + 4];
    const unsigned int* yu = (const unsigned int*)&yv;
    float oo[8] = {o0.x, o0.y, o0.z, o0.w, o1.x, o1.y, o1.z, o1.w};
    unsigned int ro[4];
#pragma unroll
    for (int d = 0; d < 4; ++d) {
      unsigned short y0 = (unsigned short)(yu[d] & 0xffffu), y1 = (unsigned short)(yu[d] >> 16);
      float v0 = b2f(y0) + ea_t * oo[d * 2 + 0];
      float v1 = b2f(y1) + ea_t * oo[d * 2 + 1];
      ro[d] = (unsigned int)f2b(v0) | ((unsigned int)f2b(v1) << 16);
    }
    *(uint4*)(y16 + off) = make_uint4(ro[0], ro[1], ro[2], ro[3]);
  }
}

// ---------------- gated RMSNorm (vectorized) ----------------
__global__ __launch_bounds__(256) void norm_kernel(
    const unsigned short* __restrict__ y16, const unsigned short* __restrict__ C1,
    const float* __restrict__ normw, unsigned short* __restrict__ yzn)
{
  int bl = blockIdx.x;
  int tid = threadIdx.x;
  int wave = tid >> 6, lane = tid & 63;
  int c8 = tid * 8;
  uint4 yv = *(const uint4*)(y16 + (size_t)bl * DSSM + c8);
  uint4 zv = *(const uint4*)(C1 + (size_t)bl * DPROJ + c8);   // z = first 2048 cols
  const unsigned int* yu = (const unsigned int*)&yv;
  const unsigned int* zu = (const unsigned int*)&zv;
  float vals[8];
  float ss = 0.f;
#pragma unroll
  for (int d = 0; d < 4; ++d) {
    unsigned short y0 = (unsigned short)(yu[d] & 0xffffu), y1 = (unsigned short)(yu[d] >> 16);
    unsigned short z0 = (unsigned short)(zu[d] & 0xffffu), z1 = (unsigned short)(zu[d] >> 16);
    float zf0 = b2f(z0), zf1 = b2f(z1);
    float v0 = b2f(y0) * (zf0 / (1.f + __expf(-zf0)));
    float v1 = b2f(y1) * (zf1 / (1.f + __expf(-zf1)));
    vals[d * 2] = v0; vals[d * 2 + 1] = v1;
    ss += v0 * v0 + v1 * v1;
  }
#pragma unroll
  for (int off = 32; off > 0; off >>= 1) ss += __shfl_down(ss, off);
  __shared__ float red[4];
  if (lane == 0) red[wave] = ss;
  __syncthreads();
  float tot = red[0] + red[1] + red[2] + red[3];
  float scale = rsqrtf(tot * (1.f / 2048.f) + 1e-5f);
  float4 w0 = *(const float4*)(normw + c8);
  float4 w1 = *(const float4*)(normw + c8 + 4);
  float ws[8] = {w0.x, w0.y, w0.z, w0.w, w1.x, w1.y, w1.z, w1.w};
  unsigned int ro[4];
#pragma unroll
  for (int d = 0; d < 4; ++d) {
    unsigned short r0 = f2b(vals[d * 2] * scale * ws[d * 2]);
    unsigned short r1 = f2b(vals[d * 2 + 1] * scale * ws[d * 2 + 1]);
    ro[d] = (unsigned int)r0 | ((unsigned int)r1 << 16);
  }
  *(uint4*)(yzn + (size_t)bl * DSSM + c8) = make_uint4(ro[0], ro[1], ro[2], ro[3]);
}

// ---------------- host launch ----------------
extern "C" void kernel_launch(void* const* d_in, const int* in_sizes, int n_in,
                              void* d_out, int out_size, void* d_ws, size_t ws_size,
                              hipStream_t stream) {
  const float* u      = (const float*)d_in[0];
  const int*   cidx   = (const int*)d_in[1];
  const float* W_in   = (const float*)d_in[2];
  const float* convw  = (const float*)d_in[3];
  const float* convb  = (const float*)d_in[4];
  const float* dtbias = (const float*)d_in[5];
  const float* A_log  = (const float*)d_in[6];
  const float* Dp     = (const float*)d_in[7];
  const float* normw  = (const float*)d_in[8];
  const float* W_out  = (const float*)d_in[9];

  char* w = (char*)d_ws;
  size_t off = 0;
  auto alloc = [&](size_t bytes) { char* p = w + off; off += (bytes + 255) & ~(size_t)255; return p; };
  unsigned short* u16     = (unsigned short*)alloc((size_t)BLTOT * DMODEL * 2);
  unsigned short* Win16   = (unsigned short*)alloc((size_t)DPROJ * DMODEL * 2);
  unsigned short* Wout16  = (unsigned short*)alloc((size_t)DMODEL * DSSM * 2);
  unsigned short* C1      = (unsigned short*)alloc((size_t)BLTOT * DPROJ * 2);
  unsigned short* x16     = (unsigned short*)alloc((size_t)BLTOT * DSSM * 2);
  unsigned short* Bg16    = (unsigned short*)alloc((size_t)BLTOT * DST * 2);
  unsigned short* Cg16    = (unsigned short*)alloc((size_t)BLTOT * DST * 2);
  float*          dtb     = (float*)alloc((size_t)BLTOT * NH * 4);
  float*          acumb   = (float*)alloc((size_t)BB * NC * NH * CS * 4);
  unsigned short* y16     = (unsigned short*)alloc((size_t)BLTOT * DSSM * 2);
  unsigned short* statesb = (unsigned short*)alloc((size_t)BB * NC * NH * DST * HD * 2);
  float*          cdb     = (float*)alloc((size_t)BB * NC * NH * 4);
  unsigned short* yzn     = (unsigned short*)alloc((size_t)BLTOT * DSSM * 2);

  const int na4 = BLTOT * DMODEL / 4, nb4 = DPROJ * DMODEL / 4, nc4 = DMODEL * DSSM / 4;
  cvt3_kernel<<<(na4 + nb4 + nc4 + 255) / 256, 256, 0, stream>>>(
      u, u16, na4, W_in, Win16, nb4, W_out, Wout16, nc4);

  // zxbcdt = u @ W_in^T   (bf16 out, ld 4384) — 128x128 tiles (best measured)
  gemm_bt<128, 1><<<dim3(BLTOT / 128, (DPROJ + 127) / 128), 256, 0, stream>>>(
      u16, Win16, C1, BLTOT, DPROJ, DMODEL, DPROJ);
  conv_kernel<<<BLTOT / 4, 256, 0, stream>>>(C1, cidx, convw, convb, dtbias, x16, Bg16, Cg16, dtb);
  d1_intra<<<BB * NC * NH, 256, 0, stream>>>(x16, Bg16, Cg16, dtb, A_log, Dp, y16, statesb, cdb, acumb);
  d2_scan<<<BB * NH * 32, 256, 0, stream>>>(statesb, cdb);
  d3_inter<<<BB * NC * NH, 256, 0, stream>>>(Cg16, statesb, acumb, y16);
  norm_kernel<<<BLTOT, 256, 0, stream>>>(y16, C1, normw, yzn);
  // out = yzn @ W_out^T   (fp32 out) — 128x64 tiles for 512 blocks (2+/CU)
  gemm_bt<64, 0><<<dim3(BLTOT / 128, DMODEL / 64), 256, 0, stream>>>(
      yzn, Wout16, (float*)d_out, BLTOT, DMODEL, DSSM, DMODEL);
}